// Round 2
// baseline (656.439 us; speedup 1.0000x reference)
//
#include <hip/hip_runtime.h>
#include <math.h>

#define NB 8
#define NE 128
#define NS 4096

typedef short s8v __attribute__((ext_vector_type(8)));   // 8 bf16 (4 VGPRs) MFMA A/B frag
typedef float f4v __attribute__((ext_vector_type(4)));   // MFMA C/D frag

__device__ __forceinline__ ushort f2bf(float f) {
  union { float f; unsigned u; } v; v.f = f;
  unsigned r = v.u + 0x7fffu + ((v.u >> 16) & 1u);  // RNE
  return (ushort)(r >> 16);
}

// ---------------- projection: Q^T [D][S], K [S][D], V^T [D][S], all bf16 ----
__global__ __launch_bounds__(64) void proj_kernel(
    const float* __restrict__ x,
    const float* __restrict__ Wq, const float* __restrict__ bq,
    const float* __restrict__ Wk, const float* __restrict__ bk,
    const float* __restrict__ Wv, const float* __restrict__ bv,
    ushort* __restrict__ Qt, ushort* __restrict__ Kn, ushort* __restrict__ Vt)
{
  const int lane = threadIdx.x;
  const int b  = blockIdx.z;
  const int s  = blockIdx.x * 64 + lane;   // coalesced dimension
  const int fh = blockIdx.y * 64;          // f-half
  const float* xb = x + (size_t)b * NE * NS;

  for (int m = 0; m < 3; ++m) {
    const float* W    = (m == 0) ? Wq : (m == 1) ? Wk : Wv;
    const float* bias = (m == 0) ? bq : (m == 1) ? bk : bv;
    #pragma unroll 1
    for (int fc = 0; fc < 4; ++fc) {
      const int fb = fh + fc * 16;
      float acc[16];
      #pragma unroll
      for (int j = 0; j < 16; ++j) acc[j] = bias[fb + j];
      #pragma unroll 4
      for (int e = 0; e < NE; ++e) {
        float xv = xb[(size_t)e * NS + s];          // coalesced across lanes
        #pragma unroll
        for (int j = 0; j < 16; ++j)
          acc[j] = fmaf(xv, W[(fb + j) * NE + e], acc[j]);  // uniform -> s_load
      }
      if (m == 1) {  // K in [S][D]: 16 contiguous bf16 = 32B per lane
        alignas(16) ushort tmp[16];
        #pragma unroll
        for (int j = 0; j < 16; ++j) tmp[j] = f2bf(acc[j]);
        uint4* dst = (uint4*)&Kn[((size_t)b * NS + s) * NE + fb];
        dst[0] = ((uint4*)tmp)[0];
        dst[1] = ((uint4*)tmp)[1];
      } else {       // Q^T / V^T in [D][S]: fully coalesced 2B stores
        ushort* P = (m == 0 ? Qt : Vt) + (size_t)b * NE * NS;
        #pragma unroll
        for (int j = 0; j < 16; ++j) P[(size_t)(fb + j) * NS + s] = f2bf(acc[j]);
      }
    }
  }
}

// ---------------- flash attention, 4 waves x 16 q-rows, KB=32 --------------
__global__ __launch_bounds__(256) void attn_kernel(
    const ushort* __restrict__ Qt, const ushort* __restrict__ Kn,
    const ushort* __restrict__ Vt, float* __restrict__ out)
{
  const int tid  = threadIdx.x;
  const int wv   = tid >> 6;
  const int lane = tid & 63;
  const int g    = lane >> 4;   // 4 lane-groups
  const int c    = lane & 15;   // col index in frags
  const int b    = blockIdx.y;
  const int qw   = blockIdx.x * 64 + wv * 16;   // this wave's q base

  const ushort* Qb = Qt + (size_t)b * NE * NS;
  const ushort* Kb = Kn + (size_t)b * NS * NE;
  const ushort* Vb = Vt + (size_t)b * NE * NS;

  __shared__ ushort P_lds[4][16 * 40];   // per-wave, row stride 40

  // lane that owns row q=c's softmax stats: group c>>2 (any lane of it), reg c&3
  const int srcl = (c >> 2) << 4;
  const int rr   = c & 3;

  // Q A-frags (hoisted): lane holds Q[q=qw+c][d = dc*32 + g*8 + i]
  s8v qf[4];
  #pragma unroll
  for (int dc = 0; dc < 4; ++dc) {
    union { s8v v; ushort u[8]; } f;
    #pragma unroll
    for (int i = 0; i < 8; ++i)
      f.u[i] = Qb[(size_t)(dc * 32 + g * 8 + i) * NS + qw + c];
    qf[dc] = f.v;
  }

  f4v o[8];
  #pragma unroll
  for (int dt = 0; dt < 8; ++dt) o[dt] = (f4v){0.f, 0.f, 0.f, 0.f};
  float mrow[4] = {-1e30f, -1e30f, -1e30f, -1e30f};
  float lsum[4] = {0.f, 0.f, 0.f, 0.f};
  const float CS = 0.12751743f;  // log2(e)/sqrt(128): softmax in exp2 domain

  for (int kt = 0; kt < NS / 32; ++kt) {
    const int k0 = kt * 32;
    // ---- S = Q.K^T for 16q x 32k (two 16-col frags)
    f4v s0 = (f4v){0.f,0.f,0.f,0.f}, s1 = (f4v){0.f,0.f,0.f,0.f};
    #pragma unroll
    for (int dc = 0; dc < 4; ++dc) {
      s8v kf0 = *(const s8v*)(Kb + ((size_t)(k0 + c)      << 7) + dc * 32 + g * 8);
      s8v kf1 = *(const s8v*)(Kb + ((size_t)(k0 + 16 + c) << 7) + dc * 32 + g * 8);
      s0 = __builtin_amdgcn_mfma_f32_16x16x32_bf16(qf[dc], kf0, s0, 0, 0, 0);
      s1 = __builtin_amdgcn_mfma_f32_16x16x32_bf16(qf[dc], kf1, s1, 0, 0, 0);
    }
    // ---- online softmax; lane (g,c) reg r holds S[q=4g+r][k'={c,16+c}]
    float sc[4], p0[4], p1[4];
    #pragma unroll
    for (int r = 0; r < 4; ++r) {
      float a0 = s0[r] * CS, a1 = s1[r] * CS;
      float mx = fmaxf(a0, a1);
      mx = fmaxf(mx, __shfl_xor(mx, 1));
      mx = fmaxf(mx, __shfl_xor(mx, 2));
      mx = fmaxf(mx, __shfl_xor(mx, 4));
      mx = fmaxf(mx, __shfl_xor(mx, 8));
      float mn  = fmaxf(mrow[r], mx);
      float scr = exp2f(mrow[r] - mn);
      mrow[r] = mn;
      p0[r] = exp2f(a0 - mn);
      p1[r] = exp2f(a1 - mn);
      float rs = p0[r] + p1[r];
      rs += __shfl_xor(rs, 1);
      rs += __shfl_xor(rs, 2);
      rs += __shfl_xor(rs, 4);
      rs += __shfl_xor(rs, 8);
      lsum[r] = lsum[r] * scr + rs;
      sc[r] = scr;
    }
    // ---- rescale factor for q=c, register-only redistribution (no LDS)
    float t0 = __shfl(sc[0], srcl);
    float t1 = __shfl(sc[1], srcl);
    float t2 = __shfl(sc[2], srcl);
    float t3 = __shfl(sc[3], srcl);
    float osc = (rr == 0) ? t0 : (rr == 1) ? t1 : (rr == 2) ? t2 : t3;
    // ---- P (bf16) -> LDS in [q][k] so PV B-frag is one contiguous b128 read
    #pragma unroll
    for (int r = 0; r < 4; ++r) {
      const int row = g * 4 + r;
      P_lds[wv][row * 40 + c]      = f2bf(p0[r]);
      P_lds[wv][row * 40 + 16 + c] = f2bf(p1[r]);
    }
    __syncthreads();   // bulletproof ordering for cross-lane P exchange
    s8v pb = *(const s8v*)&P_lds[wv][c * 40 + g * 8];  // B-frag: P[q=c][k=g*8+i]
    // ---- O^T += V^T . P^T   (A-frag = V^T rows, contiguous 16B)
    #pragma unroll
    for (int dt = 0; dt < 8; ++dt) {
      s8v vf = *(const s8v*)(Vb + (size_t)(dt * 16 + c) * NS + k0 + g * 8);
      f4v oo = o[dt] * osc;
      o[dt] = __builtin_amdgcn_mfma_f32_16x16x32_bf16(vf, pb, oo, 0, 0, 0);
    }
  }
  // ---- epilogue: denom for q=c via shuffles, write out[b][e][s] (64B runs)
  float u0 = __shfl(lsum[0], srcl);
  float u1 = __shfl(lsum[1], srcl);
  float u2 = __shfl(lsum[2], srcl);
  float u3 = __shfl(lsum[3], srcl);
  float lq = (rr == 0) ? u0 : (rr == 1) ? u1 : (rr == 2) ? u2 : u3;
  const float rinv = 1.0f / lq;
  float* ob = out + (size_t)b * NE * NS;
  #pragma unroll
  for (int dt = 0; dt < 8; ++dt) {
    #pragma unroll
    for (int r = 0; r < 4; ++r)
      ob[(size_t)(dt * 16 + g * 4 + r) * NS + qw + c] = o[dt][r] * rinv;
  }
}

extern "C" void kernel_launch(void* const* d_in, const int* in_sizes, int n_in,
                              void* d_out, int out_size, void* d_ws, size_t ws_size,
                              hipStream_t stream) {
  const float* x  = (const float*)d_in[0];
  const float* Wq = (const float*)d_in[1];
  const float* bq = (const float*)d_in[2];
  const float* Wk = (const float*)d_in[3];
  const float* bk = (const float*)d_in[4];
  const float* Wv = (const float*)d_in[5];
  const float* bv = (const float*)d_in[6];
  float* out = (float*)d_out;

  ushort* Qt = (ushort*)d_ws;                      // [B][D][S] bf16, 8 MB
  ushort* Kn = Qt + (size_t)NB * NE * NS;          // [B][S][D] bf16, 8 MB
  ushort* Vt = Kn + (size_t)NB * NE * NS;          // [B][D][S] bf16, 8 MB

  dim3 pg(NS / 64, 2, NB);
  proj_kernel<<<pg, 64, 0, stream>>>(x, Wq, bq, Wk, bk, Wv, bv, Qt, Kn, Vt);
  dim3 ag(NS / 64, NB);
  attn_kernel<<<ag, 256, 0, stream>>>(Qt, Kn, Vt, out);
}

// Round 3
// 630.832 us; speedup vs baseline: 1.0406x; 1.0406x over previous
//
#include <hip/hip_runtime.h>
#include <math.h>

#define NB 8
#define NE 128
#define NS 4096

typedef short s8v __attribute__((ext_vector_type(8)));   // 8 bf16 (4 VGPRs) MFMA A/B frag
typedef float f4v __attribute__((ext_vector_type(4)));   // MFMA C/D frag

__device__ __forceinline__ ushort f2bf(float f) {
  union { float f; unsigned u; } v; v.f = f;
  unsigned r = v.u + 0x7fffu + ((v.u >> 16) & 1u);  // RNE
  return (ushort)(r >> 16);
}

// ---------------- projection: Q^T [D][S] (pre-scaled), K [S][D], V^T [D][S] --
__global__ __launch_bounds__(64) void proj_kernel(
    const float* __restrict__ x,
    const float* __restrict__ Wq, const float* __restrict__ bq,
    const float* __restrict__ Wk, const float* __restrict__ bk,
    const float* __restrict__ Wv, const float* __restrict__ bv,
    ushort* __restrict__ Qt, ushort* __restrict__ Kn, ushort* __restrict__ Vt)
{
  const int lane = threadIdx.x;
  const int b  = blockIdx.z;
  const int s  = blockIdx.x * 64 + lane;   // coalesced dimension
  const int fh = blockIdx.y * 64;          // f-half
  const float* xb = x + (size_t)b * NE * NS;
  const float CS = 0.12751743f;  // log2(e)/sqrt(128) folded into Q

  for (int m = 0; m < 3; ++m) {
    const float* W    = (m == 0) ? Wq : (m == 1) ? Wk : Wv;
    const float* bias = (m == 0) ? bq : (m == 1) ? bk : bv;
    const float osc   = (m == 0) ? CS : 1.0f;
    #pragma unroll 1
    for (int fc = 0; fc < 4; ++fc) {
      const int fb = fh + fc * 16;
      float acc[16];
      #pragma unroll
      for (int j = 0; j < 16; ++j) acc[j] = bias[fb + j];
      #pragma unroll 4
      for (int e = 0; e < NE; ++e) {
        float xv = xb[(size_t)e * NS + s];          // coalesced across lanes
        #pragma unroll
        for (int j = 0; j < 16; ++j)
          acc[j] = fmaf(xv, W[(fb + j) * NE + e], acc[j]);  // uniform -> s_load
      }
      if (m == 1) {  // K in [S][D]: 16 contiguous bf16 = 32B per lane
        alignas(16) ushort tmp[16];
        #pragma unroll
        for (int j = 0; j < 16; ++j) tmp[j] = f2bf(acc[j]);
        uint4* dst = (uint4*)&Kn[((size_t)b * NS + s) * NE + fb];
        dst[0] = ((uint4*)tmp)[0];
        dst[1] = ((uint4*)tmp)[1];
      } else {       // Q^T / V^T in [D][S]: fully coalesced 2B stores
        ushort* P = (m == 0 ? Qt : Vt) + (size_t)b * NE * NS;
        #pragma unroll
        for (int j = 0; j < 16; ++j) P[(size_t)(fb + j) * NS + s] = f2bf(acc[j] * osc);
      }
    }
  }
}

// ---------------- flash attention, 4 waves x 16 q-rows, KB=32, no block sync -
__device__ __forceinline__ void tile_step(
    int k0, int kn0, const ushort* __restrict__ Kb, const ushort* __restrict__ Vb,
    const s8v (&qf)[4], s8v (&kf)[8], s8v (&kfn)[8], f4v (&o)[8], float (&lsum)[4],
    ushort* __restrict__ Pw, int g, int c)
{
  // prefetch next tile's K frags (L2 latency hides under this tile's work)
  #pragma unroll
  for (int dc = 0; dc < 4; ++dc) {
    kfn[2*dc]   = *(const s8v*)(Kb + ((size_t)(kn0 + c)      << 7) + dc * 32 + g * 8);
    kfn[2*dc+1] = *(const s8v*)(Kb + ((size_t)(kn0 + 16 + c) << 7) + dc * 32 + g * 8);
  }
  // this tile's V frags, issued early
  s8v vf[8];
  #pragma unroll
  for (int dt = 0; dt < 8; ++dt)
    vf[dt] = *(const s8v*)(Vb + (size_t)(dt * 16 + c) * NS + k0 + g * 8);
  // S = Q.K^T  (Q pre-scaled by log2(e)/sqrt(128))
  f4v s0 = (f4v){0.f,0.f,0.f,0.f}, s1 = (f4v){0.f,0.f,0.f,0.f};
  #pragma unroll
  for (int dc = 0; dc < 4; ++dc) {
    s0 = __builtin_amdgcn_mfma_f32_16x16x32_bf16(qf[dc], kf[2*dc],   s0, 0, 0, 0);
    s1 = __builtin_amdgcn_mfma_f32_16x16x32_bf16(qf[dc], kf[2*dc+1], s1, 0, 0, 0);
  }
  // no-max softmax: P = exp2(S); denominator accumulated, normalized once at end
  #pragma unroll
  for (int r = 0; r < 4; ++r) {
    float p0 = __builtin_amdgcn_exp2f(s0[r]);
    float p1 = __builtin_amdgcn_exp2f(s1[r]);
    lsum[r] += p0 + p1;
    const int row = g * 4 + r;
    Pw[row * 40 + c]      = f2bf(p0);
    Pw[row * 40 + 16 + c] = f2bf(p1);
  }
  // wave-local LDS round-trip: DS ops complete in order within a wave
  asm volatile("s_waitcnt lgkmcnt(0)" ::: "memory");
  __builtin_amdgcn_sched_barrier(0);
  s8v pb = *(const s8v*)&Pw[c * 40 + g * 8];  // B-frag: P[q=c][k=g*8+i]
  // O^T += V^T . P^T
  #pragma unroll
  for (int dt = 0; dt < 8; ++dt)
    o[dt] = __builtin_amdgcn_mfma_f32_16x16x32_bf16(vf[dt], pb, o[dt], 0, 0, 0);
}

__global__ __launch_bounds__(256, 2) void attn_kernel(
    const ushort* __restrict__ Qt, const ushort* __restrict__ Kn,
    const ushort* __restrict__ Vt, float* __restrict__ out)
{
  const int tid  = threadIdx.x;
  const int wv   = tid >> 6;
  const int lane = tid & 63;
  const int g    = lane >> 4;
  const int c    = lane & 15;
  const int bid  = blockIdx.x;
  const int b    = bid & 7;          // XCD-pin: all blocks of batch b on XCD b
  const int qw   = (bid >> 3) * 64 + wv * 16;

  const ushort* Qb = Qt + (size_t)b * NE * NS;
  const ushort* Kb = Kn + (size_t)b * NS * NE;
  const ushort* Vb = Vt + (size_t)b * NE * NS;

  __shared__ ushort P_lds[4][16 * 40];
  ushort* Pw = &P_lds[wv][0];

  // Q A-frags (hoisted): lane holds Q[q=qw+c][d = dc*32 + g*8 + i]
  s8v qf[4];
  #pragma unroll
  for (int dc = 0; dc < 4; ++dc) {
    union { s8v v; ushort u[8]; } f;
    #pragma unroll
    for (int i = 0; i < 8; ++i)
      f.u[i] = Qb[(size_t)(dc * 32 + g * 8 + i) * NS + qw + c];
    qf[dc] = f.v;
  }

  f4v o[8];
  #pragma unroll
  for (int dt = 0; dt < 8; ++dt) o[dt] = (f4v){0.f, 0.f, 0.f, 0.f};
  float lsum[4] = {0.f, 0.f, 0.f, 0.f};

  // preload tile 0's K frags
  s8v kfA[8], kfB[8];
  #pragma unroll
  for (int dc = 0; dc < 4; ++dc) {
    kfA[2*dc]   = *(const s8v*)(Kb + ((size_t)(c)      << 7) + dc * 32 + g * 8);
    kfA[2*dc+1] = *(const s8v*)(Kb + ((size_t)(16 + c) << 7) + dc * 32 + g * 8);
  }

  #pragma unroll 1
  for (int kt = 0; kt < NS / 32; kt += 2) {
    tile_step(kt * 32,       (kt + 1) * 32,                          Kb, Vb, qf, kfA, kfB, o, lsum, Pw, g, c);
    tile_step((kt + 1) * 32, (kt + 2 < NS/32 ? kt + 2 : kt + 1) * 32, Kb, Vb, qf, kfB, kfA, o, lsum, Pw, g, c);
  }

  // ---- epilogue: reduce denominator over the 16 k-lanes, once
  #pragma unroll
  for (int r = 0; r < 4; ++r) {
    lsum[r] += __shfl_xor(lsum[r], 1);
    lsum[r] += __shfl_xor(lsum[r], 2);
    lsum[r] += __shfl_xor(lsum[r], 4);
    lsum[r] += __shfl_xor(lsum[r], 8);
  }
  const int srcl = (c >> 2) << 4;   // a lane of group owning q=c
  const int rr   = c & 3;
  float u0 = __shfl(lsum[0], srcl);
  float u1 = __shfl(lsum[1], srcl);
  float u2 = __shfl(lsum[2], srcl);
  float u3 = __shfl(lsum[3], srcl);
  float lq = (rr == 0) ? u0 : (rr == 1) ? u1 : (rr == 2) ? u2 : u3;
  const float rinv = 1.0f / lq;
  float* ob = out + (size_t)b * NE * NS;
  #pragma unroll
  for (int dt = 0; dt < 8; ++dt) {
    #pragma unroll
    for (int r = 0; r < 4; ++r)
      ob[(size_t)(dt * 16 + g * 4 + r) * NS + qw + c] = o[dt][r] * rinv;
  }
}

extern "C" void kernel_launch(void* const* d_in, const int* in_sizes, int n_in,
                              void* d_out, int out_size, void* d_ws, size_t ws_size,
                              hipStream_t stream) {
  const float* x  = (const float*)d_in[0];
  const float* Wq = (const float*)d_in[1];
  const float* bq = (const float*)d_in[2];
  const float* Wk = (const float*)d_in[3];
  const float* bk = (const float*)d_in[4];
  const float* Wv = (const float*)d_in[5];
  const float* bv = (const float*)d_in[6];
  float* out = (float*)d_out;

  ushort* Qt = (ushort*)d_ws;                      // [B][D][S] bf16, 8 MB
  ushort* Kn = Qt + (size_t)NB * NE * NS;          // [B][S][D] bf16, 8 MB
  ushort* Vt = Kn + (size_t)NB * NE * NS;          // [B][D][S] bf16, 8 MB

  dim3 pg(NS / 64, 2, NB);
  proj_kernel<<<pg, 64, 0, stream>>>(x, Wq, bq, Wk, bk, Wv, bv, Qt, Kn, Vt);
  attn_kernel<<<dim3(NS / 64 * NB), 256, 0, stream>>>(Qt, Kn, Vt, out);
}

// Round 4
// 126.173 us; speedup vs baseline: 5.2027x; 4.9997x over previous
//
#include <hip/hip_runtime.h>
#include <math.h>

#define NB 8
#define NE 128
#define NS 4096
#define CSCALE 0.12751743f   // log2(e)/sqrt(128), folded into Q weights/bias

typedef short s8v __attribute__((ext_vector_type(8)));   // 8 bf16 MFMA A/B frag
typedef float f4v __attribute__((ext_vector_type(4)));   // MFMA C/D frag
typedef unsigned int u32;
typedef __attribute__((address_space(1))) const u32* gp1_t;
typedef __attribute__((address_space(3))) u32* lp3_t;

__device__ __forceinline__ ushort f2bf(float f) {
  union { float f; unsigned u; } v; v.f = f;
  unsigned r = v.u + 0x7fffu + ((v.u >> 16) & 1u);  // RNE
  return (ushort)(r >> 16);
}
__device__ __forceinline__ float bf2f(ushort h) {
  union { unsigned u; float f; } v; v.u = ((unsigned)h) << 16; return v.f;
}
__device__ __forceinline__ void gload_lds16(const void* g, void* l) {
  __builtin_amdgcn_global_load_lds((gp1_t)g, (lp3_t)l, 16, 0, 0);
}

// ---------------- W prep: bf16 hi/lo split (Q pre-scaled) into d_out tail ----
__global__ __launch_bounds__(256) void wprep_kernel(
    const float* __restrict__ Wq, const float* __restrict__ bq,
    const float* __restrict__ Wk, const float* __restrict__ bk,
    const float* __restrict__ Wv, const float* __restrict__ bv,
    ushort* __restrict__ Wh, ushort* __restrict__ Wl, float* __restrict__ bp)
{
  const int id = blockIdx.x * 256 + threadIdx.x;
  if (id < 3 * NE * NE) {
    const int m = id >> 14;                     // NE*NE = 16384
    const int r = id & (NE * NE - 1);
    const float* W = (m == 0) ? Wq : (m == 1) ? Wk : Wv;
    float v = W[r] * ((m == 0) ? CSCALE : 1.0f);
    ushort hi = f2bf(v);
    Wh[id] = hi;
    Wl[id] = f2bf(v - bf2f(hi));
  }
  if (id < 3 * NE) {
    const int m = id >> 7, r = id & (NE - 1);
    const float* bb = (m == 0) ? bq : (m == 1) ? bk : bv;
    bp[id] = bb[r] * ((m == 0) ? CSCALE : 1.0f);
  }
}

// ---------------- projection as bf16x3 MFMA GEMM ---------------------------
// out tiles: Qt/Vt [D][S] (C=W'*x), Kn [S][D] (C'=x^T*W'^T, operand swap)
__global__ __launch_bounds__(256, 2) void proj_gemm(
    const float* __restrict__ x, const ushort* __restrict__ Wh,
    const ushort* __restrict__ Wl, const float* __restrict__ bp,
    ushort* __restrict__ Qt, ushort* __restrict__ Kn, ushort* __restrict__ Vt)
{
  const int tid = threadIdx.x;
  const int wv = tid >> 6, lane = tid & 63;
  const int g = lane >> 4, c = lane & 15;
  const int bid = blockIdx.x;
  const int b = bid & 7;                  // XCD pin
  const int s0 = (bid >> 3) * 64;
  const float* xb = x + (size_t)b * NE * NS;

  __shared__ __align__(16) ushort xh[64][136], xl[64][136];  // x^T tile, hi/lo

  {  // stage: thread owns (s = tid&63, e-chunk), b128 writes, stride 272B
    const int ss = tid & 63, cq = tid >> 6;
    #pragma unroll
    for (int p = 0; p < 4; ++p) {
      const int ch = p * 4 + cq;          // e-chunk 0..15 (8 e each)
      union { s8v v; ushort u[8]; } H, L;
      #pragma unroll
      for (int i = 0; i < 8; ++i) {
        float v = xb[(size_t)(ch * 8 + i) * NS + s0 + ss];
        ushort hi = f2bf(v);
        H.u[i] = hi;
        L.u[i] = f2bf(v - bf2f(hi));
      }
      *(s8v*)&xh[ss][ch * 8] = H.v;
      *(s8v*)&xl[ss][ch * 8] = L.v;
    }
  }
  __syncthreads();

  f4v aq[2][4], ak[2][4], av[2][4];
  #pragma unroll
  for (int i = 0; i < 2; ++i)
    #pragma unroll
    for (int j = 0; j < 4; ++j) {
      aq[i][j] = (f4v){0.f,0.f,0.f,0.f};
      ak[i][j] = (f4v){0.f,0.f,0.f,0.f};
      av[i][j] = (f4v){0.f,0.f,0.f,0.f};
    }

  #pragma unroll
  for (int ks = 0; ks < 4; ++ks) {
    s8v xbh[4], xbl[4];
    #pragma unroll
    for (int st = 0; st < 4; ++st) {
      xbh[st] = *(const s8v*)&xh[st * 16 + c][ks * 32 + g * 8];
      xbl[st] = *(const s8v*)&xl[st * 16 + c][ks * 32 + g * 8];
    }
    #pragma unroll
    for (int ftl = 0; ftl < 2; ++ftl) {
      const int f0 = (wv * 2 + ftl) * 16;
      const size_t wo = (size_t)(f0 + c) * NE + ks * 32 + g * 8;
      s8v qh = *(const s8v*)&Wh[wo];
      s8v ql = *(const s8v*)&Wl[wo];
      s8v kh = *(const s8v*)&Wh[NE * NE + wo];
      s8v kl = *(const s8v*)&Wl[NE * NE + wo];
      s8v vh = *(const s8v*)&Wh[2 * NE * NE + wo];
      s8v vl = *(const s8v*)&Wl[2 * NE * NE + wo];
      #pragma unroll
      for (int st = 0; st < 4; ++st) {
        aq[ftl][st] = __builtin_amdgcn_mfma_f32_16x16x32_bf16(qh, xbh[st], aq[ftl][st], 0, 0, 0);
        aq[ftl][st] = __builtin_amdgcn_mfma_f32_16x16x32_bf16(qh, xbl[st], aq[ftl][st], 0, 0, 0);
        aq[ftl][st] = __builtin_amdgcn_mfma_f32_16x16x32_bf16(ql, xbh[st], aq[ftl][st], 0, 0, 0);
        av[ftl][st] = __builtin_amdgcn_mfma_f32_16x16x32_bf16(vh, xbh[st], av[ftl][st], 0, 0, 0);
        av[ftl][st] = __builtin_amdgcn_mfma_f32_16x16x32_bf16(vh, xbl[st], av[ftl][st], 0, 0, 0);
        av[ftl][st] = __builtin_amdgcn_mfma_f32_16x16x32_bf16(vl, xbh[st], av[ftl][st], 0, 0, 0);
        ak[ftl][st] = __builtin_amdgcn_mfma_f32_16x16x32_bf16(xbh[st], kh, ak[ftl][st], 0, 0, 0);
        ak[ftl][st] = __builtin_amdgcn_mfma_f32_16x16x32_bf16(xbl[st], kh, ak[ftl][st], 0, 0, 0);
        ak[ftl][st] = __builtin_amdgcn_mfma_f32_16x16x32_bf16(xbh[st], kl, ak[ftl][st], 0, 0, 0);
      }
    }
  }

  ushort* Qtb = Qt + (size_t)b * NE * NS;
  ushort* Vtb = Vt + (size_t)b * NE * NS;
  ushort* Knb = Kn + (size_t)b * NS * NE;
  #pragma unroll
  for (int ftl = 0; ftl < 2; ++ftl) {
    const int f0 = (wv * 2 + ftl) * 16;
    #pragma unroll
    for (int r = 0; r < 4; ++r) {            // Q,V: row f = f0+4g+r, col s
      const int f = f0 + 4 * g + r;
      const float bqv = bp[f];
      const float bvv = bp[2 * NE + f];
      #pragma unroll
      for (int st = 0; st < 4; ++st) {
        Qtb[(size_t)f * NS + s0 + st * 16 + c] = f2bf(aq[ftl][st][r] + bqv);
        Vtb[(size_t)f * NS + s0 + st * 16 + c] = f2bf(av[ftl][st][r] + bvv);
      }
    }
    const float bkv = bp[NE + f0 + c];       // K: row s = s0+st*16+4g+r, col f = f0+c
    #pragma unroll
    for (int st = 0; st < 4; ++st)
      #pragma unroll
      for (int r = 0; r < 4; ++r)
        Knb[(size_t)(s0 + st * 16 + 4 * g + r) * NE + f0 + c] = f2bf(ak[ftl][st][r] + bkv);
  }
}

// ---------------- flash attention: LDS-staged K/V tiles, KVB=64 ------------
__global__ __launch_bounds__(256, 2) void attn_kernel(
    const ushort* __restrict__ Qt, const ushort* __restrict__ Kn,
    const ushort* __restrict__ Vt, float* __restrict__ out)
{
  const int tid = threadIdx.x;
  const int wv = tid >> 6, lane = tid & 63;
  const int g = lane >> 4, c = lane & 15;
  const int bid = blockIdx.x;
  const int b = bid & 7;                       // XCD pin: batch b -> XCD b
  const int qw = (bid >> 3) * 64 + wv * 16;

  const ushort* Qb = Qt + (size_t)b * NE * NS;
  const char*   Kb = (const char*)(Kn + (size_t)b * NS * NE);
  const char*   Vb = (const char*)(Vt + (size_t)b * NE * NS);

  __shared__ __align__(16) char ldsK[2][16384];     // K tile [64 k][128 d] bf16
  __shared__ __align__(16) char ldsV[2][16384];     // V^T tile [128 d][64 k] bf16
  __shared__ __align__(16) ushort P_lds[4][16 * 72];
  ushort* Pw = &P_lds[wv][0];

  // Q A-frags: lane holds Q[qw+c][dc*32+g*8+i]
  s8v qf[4];
  #pragma unroll
  for (int dc = 0; dc < 4; ++dc) {
    union { s8v v; ushort u[8]; } f;
    #pragma unroll
    for (int i = 0; i < 8; ++i)
      f.u[i] = Qb[(size_t)(dc * 32 + g * 8 + i) * NS + qw + c];
    qf[dc] = f.v;
  }

  // stage tile kt into buffer buf: linear LDS dest, inverse-swizzled source
  auto stage = [&](int buf, int kt) {
    const char* Ksrc = Kb + (size_t)kt * (64 * 256);   // contiguous 16KB
    #pragma unroll
    for (int p = 0; p < 4; ++p) {
      const int off = wv * 4096 + p * 1024;            // wave-uniform dest
      const int lo = off + lane * 16;
      const int row = lo >> 8;
      gload_lds16(Ksrc + (lo ^ ((row & 7) << 4)), &ldsK[buf][off]);
    }
    #pragma unroll
    for (int p = 0; p < 4; ++p) {
      const int off = wv * 4096 + p * 1024;
      const int lo = off + lane * 16;
      const int row = lo >> 7;                         // d (128B rows)
      const int inner = (lo & 127) ^ ((row & 7) << 4);
      gload_lds16(Vb + (size_t)row * (NS * 2) + kt * 128 + inner, &ldsV[buf][off]);
    }
  };

  f4v o[8];
  #pragma unroll
  for (int dt = 0; dt < 8; ++dt) o[dt] = (f4v){0.f, 0.f, 0.f, 0.f};
  float lsum[4] = {0.f, 0.f, 0.f, 0.f};

  stage(0, 0);
  __syncthreads();   // drains vmcnt(0): tile 0 resident

  #pragma unroll 1
  for (int kt = 0; kt < NS / 64; ++kt) {
    const int cur = kt & 1;
    if (kt + 1 < NS / 64) stage(cur ^ 1, kt + 1);   // async, drains at loop-end barrier
    const char* bK = ldsK[cur];
    const char* bV = ldsV[cur];

    // ---- S = Q.K^T (16q x 64k), swizzled ds_read_b128
    f4v s[4];
    #pragma unroll
    for (int kc = 0; kc < 4; ++kc) {
      s[kc] = (f4v){0.f, 0.f, 0.f, 0.f};
      s8v kk[4];
      #pragma unroll
      for (int dc = 0; dc < 4; ++dc)
        kk[dc] = *(const s8v*)(bK + (kc * 16 + c) * 256 + ((dc * 64 + g * 16) ^ ((c & 7) << 4)));
      #pragma unroll
      for (int dc = 0; dc < 4; ++dc)
        s[kc] = __builtin_amdgcn_mfma_f32_16x16x32_bf16(qf[dc], kk[dc], s[kc], 0, 0, 0);
    }
    // ---- V frags (issue reads early; drained by the lgkmcnt below)
    s8v vf[8][2];
    #pragma unroll
    for (int dt = 0; dt < 8; ++dt)
      #pragma unroll
      for (int ks = 0; ks < 2; ++ks)
        vf[dt][ks] = *(const s8v*)(bV + (dt * 16 + c) * 128 + ((ks * 64 + g * 16) ^ ((c & 7) << 4)));
    // ---- no-max softmax: P = exp2(S), denom accumulated
    #pragma unroll
    for (int kc = 0; kc < 4; ++kc)
      #pragma unroll
      for (int r = 0; r < 4; ++r) {
        float p = __builtin_amdgcn_exp2f(s[kc][r]);
        lsum[r] += p;
        Pw[(4 * g + r) * 72 + kc * 16 + c] = f2bf(p);
      }
    asm volatile("s_waitcnt lgkmcnt(0)" ::: "memory");
    __builtin_amdgcn_sched_barrier(0);
    s8v pb[2];
    #pragma unroll
    for (int ks = 0; ks < 2; ++ks)
      pb[ks] = *(const s8v*)((const char*)Pw + c * 144 + ks * 64 + g * 16);
    // ---- O^T += V^T . P^T
    #pragma unroll
    for (int dt = 0; dt < 8; ++dt)
      #pragma unroll
      for (int ks = 0; ks < 2; ++ks)
        o[dt] = __builtin_amdgcn_mfma_f32_16x16x32_bf16(vf[dt][ks], pb[ks], o[dt], 0, 0, 0);
    __syncthreads();   // drains vmcnt (next tile staged) + all waves done with cur
  }

  // ---- epilogue: reduce denom over 16 k-lanes, redistribute, write out
  #pragma unroll
  for (int r = 0; r < 4; ++r) {
    lsum[r] += __shfl_xor(lsum[r], 1);
    lsum[r] += __shfl_xor(lsum[r], 2);
    lsum[r] += __shfl_xor(lsum[r], 4);
    lsum[r] += __shfl_xor(lsum[r], 8);
  }
  const int srcl = (c >> 2) << 4;
  const int rr = c & 3;
  float u0 = __shfl(lsum[0], srcl);
  float u1 = __shfl(lsum[1], srcl);
  float u2 = __shfl(lsum[2], srcl);
  float u3 = __shfl(lsum[3], srcl);
  float lq = (rr == 0) ? u0 : (rr == 1) ? u1 : (rr == 2) ? u2 : u3;
  const float rinv = 1.0f / lq;
  float* ob = out + (size_t)b * NE * NS;
  #pragma unroll
  for (int dt = 0; dt < 8; ++dt)
    #pragma unroll
    for (int r = 0; r < 4; ++r)
      ob[(size_t)(dt * 16 + g * 4 + r) * NS + qw + c] = o[dt][r] * rinv;
}

extern "C" void kernel_launch(void* const* d_in, const int* in_sizes, int n_in,
                              void* d_out, int out_size, void* d_ws, size_t ws_size,
                              hipStream_t stream) {
  const float* x  = (const float*)d_in[0];
  const float* Wq = (const float*)d_in[1];
  const float* bq = (const float*)d_in[2];
  const float* Wk = (const float*)d_in[3];
  const float* bk = (const float*)d_in[4];
  const float* Wv = (const float*)d_in[5];
  const float* bv = (const float*)d_in[6];
  float* out = (float*)d_out;

  ushort* Qt = (ushort*)d_ws;                      // [B][D][S] bf16, 8 MB
  ushort* Kn = Qt + (size_t)NB * NE * NS;          // [B][S][D] bf16, 8 MB
  ushort* Vt = Kn + (size_t)NB * NE * NS;          // [B][D][S] bf16, 8 MB

  // W' scratch in the tail of d_out (fully overwritten by attn afterwards)
  char* outB = (char*)d_out + (size_t)out_size * 4 - 262144;
  ushort* Wh = (ushort*)outB;                      // [3][128][128] bf16 hi
  ushort* Wl = Wh + 3 * NE * NE;                   // lo
  float*  bp = (float*)(Wl + 3 * NE * NE);         // [3][128] fp32

  wprep_kernel<<<dim3(192), 256, 0, stream>>>(Wq, bq, Wk, bk, Wv, bv, Wh, Wl, bp);
  proj_gemm<<<dim3(NS / 64 * NB), 256, 0, stream>>>(x, Wh, Wl, bp, Qt, Kn, Vt);
  attn_kernel<<<dim3(NS / 64 * NB), 256, 0, stream>>>(Qt, Kn, Vt, out);
}

// Round 6
// 118.037 us; speedup vs baseline: 5.5613x; 1.0689x over previous
//
#include <hip/hip_runtime.h>
#include <math.h>

#define NB 8
#define NE 128
#define NS 4096
#define CSCALE 0.12751743f   // log2(e)/sqrt(128), folded into Q weights/bias

typedef short s8v __attribute__((ext_vector_type(8)));    // 8 bf16 MFMA A/B frag
typedef float f4v __attribute__((ext_vector_type(4)));    // 16x16 C frag
typedef float f16v __attribute__((ext_vector_type(16)));  // 32x32 C frag
typedef unsigned int u32;
typedef unsigned int u2v __attribute__((ext_vector_type(2)));
typedef __attribute__((address_space(1))) const u32* gp1_t;
typedef __attribute__((address_space(3))) u32* lp3_t;

__device__ __forceinline__ ushort f2bf(float f) {
  union { float f; unsigned u; } v; v.f = f;
  unsigned r = v.u + 0x7fffu + ((v.u >> 16) & 1u);  // RNE
  return (ushort)(r >> 16);
}
__device__ __forceinline__ float bf2f(ushort h) {
  union { unsigned u; float f; } v; v.u = ((unsigned)h) << 16; return v.f;
}
__device__ __forceinline__ void gload_lds16(const void* g, void* l) {
  __builtin_amdgcn_global_load_lds((gp1_t)g, (lp3_t)l, 16, 0, 0);
}
__device__ __forceinline__ u32 cvtpk(float lo, float hi) {
  u32 r;
  asm("v_cvt_pk_bf16_f32 %0, %1, %2" : "=v"(r) : "v"(lo), "v"(hi));
  return r;
}
// split 8 consecutive fp32 into bf16 hi + lo fragments (bf16x3 accuracy)
__device__ __forceinline__ void split8(const float* __restrict__ p, float scale,
                                       s8v& hi, s8v& lo) {
  union { s8v v; ushort u[8]; } H, L;
  #pragma unroll
  for (int i = 0; i < 8; ++i) {
    float v = p[i] * scale;
    ushort h = f2bf(v);
    H.u[i] = h;
    L.u[i] = f2bf(v - bf2f(h));
  }
  hi = H.v; lo = L.v;
}

// ---------------- projection as bf16x3 MFMA GEMM ---------------------------
// outputs: Qn [S][D] (pre-scaled), Kn [S][D], Vt [D][S]; W split done in-reg.
__global__ __launch_bounds__(256, 2) void proj_gemm(
    const float* __restrict__ x,
    const float* __restrict__ Wq, const float* __restrict__ bq,
    const float* __restrict__ Wk, const float* __restrict__ bk,
    const float* __restrict__ Wv, const float* __restrict__ bv,
    ushort* __restrict__ Qn, ushort* __restrict__ Kn, ushort* __restrict__ Vt)
{
  const int tid = threadIdx.x;
  const int wv = tid >> 6, lane = tid & 63;
  const int g = lane >> 4, c = lane & 15;
  const int bid = blockIdx.x;
  const int b = bid & 7;                  // XCD pin
  const int s0 = (bid >> 3) * 64;
  const float* xb = x + (size_t)b * NE * NS;

  __shared__ __align__(16) ushort xh[64][136], xl[64][136];  // x^T tile, hi/lo

  {  // stage: thread owns (s = tid&63, e-chunk), b128 writes
    const int ss = tid & 63, cq = tid >> 6;
    #pragma unroll
    for (int p = 0; p < 4; ++p) {
      const int ch = p * 4 + cq;          // e-chunk 0..15 (8 e each)
      union { s8v v; ushort u[8]; } H, L;
      #pragma unroll
      for (int i = 0; i < 8; ++i) {
        float v = xb[(size_t)(ch * 8 + i) * NS + s0 + ss];
        ushort hi = f2bf(v);
        H.u[i] = hi;
        L.u[i] = f2bf(v - bf2f(hi));
      }
      *(s8v*)&xh[ss][ch * 8] = H.v;
      *(s8v*)&xl[ss][ch * 8] = L.v;
    }
  }
  __syncthreads();

  f4v aq[2][4], ak[2][4], av[2][4];
  #pragma unroll
  for (int i = 0; i < 2; ++i)
    #pragma unroll
    for (int j = 0; j < 4; ++j) {
      aq[i][j] = (f4v){0.f,0.f,0.f,0.f};
      ak[i][j] = (f4v){0.f,0.f,0.f,0.f};
      av[i][j] = (f4v){0.f,0.f,0.f,0.f};
    }

  #pragma unroll
  for (int ks = 0; ks < 4; ++ks) {
    s8v xbh[4], xbl[4];
    #pragma unroll
    for (int st = 0; st < 4; ++st) {
      xbh[st] = *(const s8v*)&xh[st * 16 + c][ks * 32 + g * 8];
      xbl[st] = *(const s8v*)&xl[st * 16 + c][ks * 32 + g * 8];
    }
    #pragma unroll
    for (int ftl = 0; ftl < 2; ++ftl) {
      const int f0 = (wv * 2 + ftl) * 16;
      const size_t wo = (size_t)(f0 + c) * NE + ks * 32 + g * 8;
      s8v qh, ql, kh, kl, vh, vl;
      split8(Wq + wo, CSCALE, qh, ql);
      split8(Wk + wo, 1.0f,   kh, kl);
      split8(Wv + wo, 1.0f,   vh, vl);
      #pragma unroll
      for (int st = 0; st < 4; ++st) {
        // Q (swapped operands -> C[s][f], like K)
        aq[ftl][st] = __builtin_amdgcn_mfma_f32_16x16x32_bf16(xbh[st], qh, aq[ftl][st], 0, 0, 0);
        aq[ftl][st] = __builtin_amdgcn_mfma_f32_16x16x32_bf16(xbl[st], qh, aq[ftl][st], 0, 0, 0);
        aq[ftl][st] = __builtin_amdgcn_mfma_f32_16x16x32_bf16(xbh[st], ql, aq[ftl][st], 0, 0, 0);
        // V (C[f][s])
        av[ftl][st] = __builtin_amdgcn_mfma_f32_16x16x32_bf16(vh, xbh[st], av[ftl][st], 0, 0, 0);
        av[ftl][st] = __builtin_amdgcn_mfma_f32_16x16x32_bf16(vh, xbl[st], av[ftl][st], 0, 0, 0);
        av[ftl][st] = __builtin_amdgcn_mfma_f32_16x16x32_bf16(vl, xbh[st], av[ftl][st], 0, 0, 0);
        // K (C[s][f])
        ak[ftl][st] = __builtin_amdgcn_mfma_f32_16x16x32_bf16(xbh[st], kh, ak[ftl][st], 0, 0, 0);
        ak[ftl][st] = __builtin_amdgcn_mfma_f32_16x16x32_bf16(xbl[st], kh, ak[ftl][st], 0, 0, 0);
        ak[ftl][st] = __builtin_amdgcn_mfma_f32_16x16x32_bf16(xbh[st], kl, ak[ftl][st], 0, 0, 0);
      }
    }
  }

  ushort* Qnb = Qn + (size_t)b * NS * NE;
  ushort* Knb = Kn + (size_t)b * NS * NE;
  ushort* Vtb = Vt + (size_t)b * NE * NS;
  #pragma unroll
  for (int ftl = 0; ftl < 2; ++ftl) {
    const int f0 = (wv * 2 + ftl) * 16;
    #pragma unroll
    for (int r = 0; r < 4; ++r) {            // V: row f = f0+4g+r, col s
      const int f = f0 + 4 * g + r;
      const float bvv = bv[f];
      #pragma unroll
      for (int st = 0; st < 4; ++st)
        Vtb[(size_t)f * NS + s0 + st * 16 + c] = f2bf(av[ftl][st][r] + bvv);
    }
    const float bqv = bq[f0 + c] * CSCALE;   // Q,K: row s = s0+st*16+4g+r, col f = f0+c
    const float bkv = bk[f0 + c];
    #pragma unroll
    for (int st = 0; st < 4; ++st)
      #pragma unroll
      for (int r = 0; r < 4; ++r) {
        const size_t ro = (size_t)(s0 + st * 16 + 4 * g + r) * NE + f0 + c;
        Qnb[ro] = f2bf(aq[ftl][st][r] + bqv);
        Knb[ro] = f2bf(ak[ftl][st][r] + bkv);
      }
  }
}

// ------- flash attention: 32x32 MFMA, swapped QK^T, in-register softmax ----
// 4 waves x 32 q/wave = 128 q/block; K/V LDS double-buffered, KVB=64.
__global__ __launch_bounds__(256) void attn_kernel(
    const ushort* __restrict__ Qn, const ushort* __restrict__ Kn,
    const ushort* __restrict__ Vt, float* __restrict__ out)
{
  const int tid = threadIdx.x;
  const int wv = tid >> 6, lane = tid & 63;
  const int h = lane >> 5, q5 = lane & 31;
  const int bid = blockIdx.x;
  const int b = bid & 7;                       // XCD pin: batch b -> XCD b
  const int qw = (bid >> 3) * 128 + wv * 32;   // wave's 32-q strip

  const ushort* Qb = Qn + (size_t)b * NS * NE;
  const char*   Kb = (const char*)(Kn + (size_t)b * NS * NE);
  const char*   Vb = (const char*)(Vt + (size_t)b * NE * NS);

  __shared__ __align__(16) char ldsK[2][16384];   // K tile [64 k][128 d] bf16 (xor-swz)
  __shared__ __align__(16) char ldsV[2][16384];   // V^T tile [128 d][64 k] bf16 (xor-swz)

  // Q B-frags: lane holds Q[qw+q5][d = dc*16 + h*8 + j], contiguous 16B
  s8v qf[8];
  #pragma unroll
  for (int dc = 0; dc < 8; ++dc)
    qf[dc] = *(const s8v*)(Qb + (size_t)(qw + q5) * NE + dc * 16 + h * 8);

  auto stage = [&](int buf, int kt) {
    const char* Ksrc = Kb + (size_t)kt * (64 * 256);   // contiguous 16KB
    #pragma unroll
    for (int p = 0; p < 4; ++p) {
      const int off = wv * 4096 + p * 1024;            // wave-uniform dest
      const int lo = off + lane * 16;
      const int row = lo >> 8;
      gload_lds16(Ksrc + (lo ^ ((row & 7) << 4)), &ldsK[buf][off]);
    }
    #pragma unroll
    for (int p = 0; p < 4; ++p) {
      const int off = wv * 4096 + p * 1024;
      const int lo = off + lane * 16;
      const int row = lo >> 7;                         // d (128B rows)
      const int inner = (lo & 127) ^ ((row & 7) << 4);
      gload_lds16(Vb + (size_t)row * (NS * 2) + kt * 128 + inner, &ldsV[buf][off]);
    }
  };

  f16v o[4];
  #pragma unroll
  for (int dt = 0; dt < 4; ++dt)
    o[dt] = (f16v){0,0,0,0,0,0,0,0,0,0,0,0,0,0,0,0};
  float lsum = 0.f;

  stage(0, 0);
  asm volatile("s_waitcnt vmcnt(0)" ::: "memory");  // source-guaranteed drain
  __syncthreads();

  #pragma unroll 1
  for (int kt = 0; kt < NS / 64; ++kt) {
    const int cur = kt & 1;
    if (kt + 1 < NS / 64) stage(cur ^ 1, kt + 1);
    const char* bK = ldsK[cur];
    const char* bV = ldsV[cur];

    #pragma unroll
    for (int kc = 0; kc < 2; ++kc) {
      // ---- S^T[k][q] = K . Q^T : A = K rows (32 k), B = Q regs
      f16v s = (f16v){0,0,0,0,0,0,0,0,0,0,0,0,0,0,0,0};
      #pragma unroll
      for (int dc = 0; dc < 8; ++dc) {
        s8v kf = *(const s8v*)(bK + (kc * 32 + q5) * 256 + ((dc * 32 + h * 16) ^ ((q5 & 7) << 4)));
        s = __builtin_amdgcn_mfma_f32_32x32x16_bf16(kf, qf[dc], s, 0, 0, 0);
      }
      // ---- P = exp2(S) in-register; lane's 16 values all at q = q5
      float p[16];
      #pragma unroll
      for (int r = 0; r < 16; ++r) {
        p[r] = __builtin_amdgcn_exp2f(s[r]);
        lsum += p[r];
      }
      // ---- build PV B-frags in-register: cvt_pk pairs + permlane32_swap
      #pragma unroll
      for (int ksl = 0; ksl < 2; ++ksl) {
        const int r0 = ksl * 8;
        u32 A = cvtpk(p[r0 + 0], p[r0 + 1]);
        u32 B = cvtpk(p[r0 + 4], p[r0 + 5]);
        u32 C = cvtpk(p[r0 + 2], p[r0 + 3]);
        u32 D = cvtpk(p[r0 + 6], p[r0 + 7]);
        u2v rAB = __builtin_amdgcn_permlane32_swap(A, B, false, false);
        u2v rCD = __builtin_amdgcn_permlane32_swap(C, D, false, false);
        union { s8v v; u32 w[4]; } P;
        P.w[0] = rAB[0]; P.w[1] = rCD[0]; P.w[2] = rAB[1]; P.w[3] = rCD[1];
        const int ks = kc * 2 + ksl;   // 16-k slice within tile
        // ---- O^T[d][q] += V^T . P : A = V^T rows (32 d), B = P frag
        #pragma unroll
        for (int dt = 0; dt < 4; ++dt) {
          s8v vf = *(const s8v*)(bV + (dt * 32 + q5) * 128 + ((ks * 32 + h * 16) ^ ((q5 & 7) << 4)));
          o[dt] = __builtin_amdgcn_mfma_f32_32x32x16_bf16(vf, P.v, o[dt], 0, 0, 0);
        }
      }
    }
    asm volatile("s_waitcnt vmcnt(0)" ::: "memory");  // next tile fully in LDS
    __syncthreads();   // all waves done reading cur + staged next
  }

  // ---- epilogue: denom = own 32 k's + other half's 32 k's; per-lane scalar
  lsum += __shfl_xor(lsum, 32);
  const float rinv = 1.0f / lsum;
  float* ob = out + (size_t)b * NE * NS;
  #pragma unroll
  for (int dt = 0; dt < 4; ++dt)
    #pragma unroll
    for (int r = 0; r < 16; ++r) {
      const int e = dt * 32 + (r & 3) + 8 * (r >> 2) + 4 * h;
      ob[(size_t)e * NS + qw + q5] = o[dt][r] * rinv;
    }
}

extern "C" void kernel_launch(void* const* d_in, const int* in_sizes, int n_in,
                              void* d_out, int out_size, void* d_ws, size_t ws_size,
                              hipStream_t stream) {
  const float* x  = (const float*)d_in[0];
  const float* Wq = (const float*)d_in[1];
  const float* bq = (const float*)d_in[2];
  const float* Wk = (const float*)d_in[3];
  const float* bk = (const float*)d_in[4];
  const float* Wv = (const float*)d_in[5];
  const float* bv = (const float*)d_in[6];
  float* out = (float*)d_out;

  ushort* Qn = (ushort*)d_ws;                      // [B][S][D] bf16, 8 MB
  ushort* Kn = Qn + (size_t)NB * NS * NE;          // [B][S][D] bf16, 8 MB
  ushort* Vt = Kn + (size_t)NB * NS * NE;          // [B][D][S] bf16, 8 MB

  proj_gemm<<<dim3(NS / 64 * NB), 256, 0, stream>>>(x, Wq, bq, Wk, bk, Wv, bv, Qn, Kn, Vt);
  attn_kernel<<<dim3(NS / 128 * NB), 256, 0, stream>>>(Qn, Kn, Vt, out);
}